// Round 13
// baseline (171.459 us; speedup 1.0000x reference)
//
#include <hip/hip_runtime.h>
#include <hip/hip_bf16.h>
#include <stdint.h>

#define NN 100000
#define EE 1600000
#define CAP 80            // srclist slots per dst (max unique in-degree ~70)
#define SBK 1664          // dsts per super-stream (13*128 -> fine buckets stay 128-aligned)
#define NS 61             // super-streams: 61*1664 = 101504 >= NN
#define NF 13             // fine buckets per stream
#define NBF 793           // NS*NF fine buckets; d0 = b*128
#define GBIN 391          // bin1 blocks (4096 pairs each)
#define S1 256            // slots per (stream, bin1-block) slice [mean 134, sigma 11.5]
#define NB2 4             // bin2 blocks per stream
#define SEGS 98           // bin1 slices per bin2 block (391 = 3*98 + 97)
#define S2 1536           // slots per (fine, bin2-block) slice [mean ~1010, sigma ~31]
#define HTS 8192          // per-bucket LDS hash slots
#define EMPTY 0xFFFFFFFFu
#define GLIN 1563         // linear blocks: ceil(NN/64)

typedef float fx2 __attribute__((ext_vector_type(2)));   // NT-store-compatible

__device__ __forceinline__ unsigned int mix32(unsigned int x){
  x ^= x >> 16; x *= 0x7feb352du;
  x ^= x >> 15; x *= 0x846ca68bu;
  x ^= x >> 16;
  return x;
}

// Fused linear + bin1. Bin1 scatters into 61 super-streams only: per-block
// active write window = 61 slices x 1KB = 61KB (L2-resident, ~no write amp),
// positions from LDS counters, zero global atomics.
extern "C" __global__ __launch_bounds__(256)
void k_prep(const float* __restrict__ x, const float* __restrict__ W,
            const float* __restrict__ bias, __hip_bfloat16* __restrict__ hb,
            const int* __restrict__ ei, int* __restrict__ c1,
            unsigned int* __restrict__ buf1){
  __shared__ __align__(16) char sm[17920];
  const int tid = threadIdx.x;
  const int bid = blockIdx.x;
  const bool isbin = (bid < GBIN);
  const int sub = isbin ? bid : (bid - GBIN);

  if (!isbin){
    // ---------- linear: 64 nodes/block, W and x staged bf16 ----------
    __hip_bfloat16 (*wt)[72] = reinterpret_cast<__hip_bfloat16(*)[72]>(sm);        // 9216B wt[i][o]=W[o][i]
    __hip_bfloat16 (*xs)[68] = reinterpret_cast<__hip_bfloat16(*)[68]>(sm + 9216); // 8704B xs[i][n]
    const int lane = tid & 63;
    const int wv   = tid >> 6;
    #pragma unroll
    for (int r = 0; r < 16; ++r){
      int i = r*4 + wv;
      wt[i][lane] = __float2bfloat16(W[lane*64 + i]);
    }
    const int nbase = sub * 64;
    #pragma unroll
    for (int r = 0; r < 4; ++r){
      int idx = r*256 + tid;          // float4 slot in [64][16]
      int nl  = idx >> 4;
      int c4  = idx & 15;
      int n   = nbase + nl;
      float4 v = make_float4(0.f,0.f,0.f,0.f);
      if (n < NN) v = reinterpret_cast<const float4*>(x)[(size_t)n*16 + c4];
      xs[c4*4+0][nl] = __float2bfloat16(v.x);
      xs[c4*4+1][nl] = __float2bfloat16(v.y);
      xs[c4*4+2][nl] = __float2bfloat16(v.z);
      xs[c4*4+3][nl] = __float2bfloat16(v.w);
    }
    __syncthreads();

    const int og  = tid & 7;
    const int nl0 = (tid >> 3) * 2;   // 2 nodes per thread
    float acc[2][8];
    #pragma unroll
    for (int t=0;t<2;++t){
      #pragma unroll
      for (int j=0;j<8;++j) acc[t][j]=0.f;
    }
    #pragma unroll 4
    for (int i=0;i<64;++i){
      uint4 wq = *reinterpret_cast<const uint4*>(&wt[i][og*8]);
      float w0 = __uint_as_float(wq.x << 16), w1 = __uint_as_float(wq.x & 0xFFFF0000u);
      float w2 = __uint_as_float(wq.y << 16), w3 = __uint_as_float(wq.y & 0xFFFF0000u);
      float w4 = __uint_as_float(wq.z << 16), w5 = __uint_as_float(wq.z & 0xFFFF0000u);
      float w6 = __uint_as_float(wq.w << 16), w7 = __uint_as_float(wq.w & 0xFFFF0000u);
      unsigned xv = *reinterpret_cast<const unsigned*>(&xs[i][nl0]);  // 2 bf16
      float x0 = __uint_as_float(xv << 16);
      float x1 = __uint_as_float(xv & 0xFFFF0000u);
      acc[0][0] += x0*w0; acc[0][1] += x0*w1; acc[0][2] += x0*w2; acc[0][3] += x0*w3;
      acc[0][4] += x0*w4; acc[0][5] += x0*w5; acc[0][6] += x0*w6; acc[0][7] += x0*w7;
      acc[1][0] += x1*w0; acc[1][1] += x1*w1; acc[1][2] += x1*w2; acc[1][3] += x1*w3;
      acc[1][4] += x1*w4; acc[1][5] += x1*w5; acc[1][6] += x1*w6; acc[1][7] += x1*w7;
    }
    float4 b0 = reinterpret_cast<const float4*>(bias)[og*2];
    float4 b1 = reinterpret_cast<const float4*>(bias)[og*2+1];
    float bb[8] = {b0.x,b0.y,b0.z,b0.w,b1.x,b1.y,b1.z,b1.w};
    #pragma unroll
    for (int t=0;t<2;++t){
      int n = nbase + nl0 + t;
      if (n < NN){
        union { uint4 u4; __hip_bfloat16 v[8]; } pk;
        #pragma unroll
        for (int j=0;j<8;++j) pk.v[j] = __float2bfloat16(acc[t][j] + bb[j]);
        reinterpret_cast<uint4*>(&hb[(size_t)n*64])[og] = pk.u4;
      }
    }
  } else {
    // ---------- bin1: 4096 pairs/block -> 61 super-stream slices ----------
    int* lcnt = reinterpret_cast<int*>(sm);   // [NS]
    for (int i = tid; i < NS; i += 256) lcnt[i] = 0;
    __syncthreads();
    const int base4 = sub * 1024;
    const int4* ea4 = reinterpret_cast<const int4*>(ei);
    const int4* ec4 = reinterpret_cast<const int4*>(ei + EE);
    #pragma unroll
    for (int r = 0; r < 4; ++r){
      int idx = base4 + r*256 + tid;
      if (idx < (EE >> 2)){
        int4 A = ea4[idx], C = ec4[idx];
#define BIN1(a,c) { \
        int g1 = (c) / SBK; int dl1 = (c) - g1*SBK; \
        int p1 = atomicAdd(&lcnt[g1], 1); \
        if (p1 < S1) buf1[((size_t)g1*GBIN + sub)*S1 + p1] = ((unsigned)(a) << 11) | (unsigned)dl1; \
        int g2 = (a) / SBK; int dl2 = (a) - g2*SBK; \
        int p2 = atomicAdd(&lcnt[g2], 1); \
        if (p2 < S1) buf1[((size_t)g2*GBIN + sub)*S1 + p2] = ((unsigned)(c) << 11) | (unsigned)dl2; }
        BIN1(A.x, C.x) BIN1(A.y, C.y) BIN1(A.z, C.z) BIN1(A.w, C.w)
#undef BIN1
      }
    }
    __syncthreads();
    for (int g = tid; g < NS; g += 256){
      int c = lcnt[g];
      c1[g*GBIN + sub] = (c < S1) ? c : S1;
    }
  }
}

// bin2: one block per (stream, quarter). Re-bins ~13K entries into the
// stream's 13 fine buckets; active write window 13 x 6KB = 78KB (L2-hot).
extern "C" __global__ __launch_bounds__(256)
void k_bin2(const int* __restrict__ c1, const unsigned int* __restrict__ buf1,
            int* __restrict__ c2, unsigned int* __restrict__ buf2){
  __shared__ int scnt[SEGS];
  __shared__ int lcnt[NF];
  const int tid = threadIdx.x;
  const int g   = blockIdx.x / NB2;
  const int kb  = blockIdx.x % NB2;
  const int s0  = kb * SEGS;
  const int se  = (s0 + SEGS < GBIN) ? (s0 + SEGS) : GBIN;
  const int nseg = se - s0;
  for (int i = tid; i < nseg; i += 256) scnt[i] = c1[g*GBIN + s0 + i];
  if (tid < NF) lcnt[tid] = 0;
  __syncthreads();

  const unsigned int* src = buf1 + ((size_t)g*GBIN + s0)*S1;
  const int tot = nseg * S1;
  for (int i = tid; i < tot; i += 256){
    int seg = i >> 8;          // S1 = 256
    int k   = i & 255;
    if (k < scnt[seg]){
      unsigned v  = src[i];
      unsigned dl = v & 2047;              // dst offset within stream [0,1664)
      unsigned f  = dl >> 7;               // fine bucket [0,13)
      unsigned e2 = ((v >> 11) << 7) | (dl & 127);   // src<<7 | dst&127
      int p = atomicAdd(&lcnt[f], 1);
      if (p < S2) buf2[(((size_t)(g*NF + f))*NB2 + kb)*S2 + p] = e2;
    }
  }
  __syncthreads();
  if (tid < NF){
    int c = lcnt[tid];
    c2[(g*NF + tid)*NB2 + kb] = (c < S2) ? c : S2;
  }
}

// One block per fine bucket (128 dsts, d0 = b*128): dedup 4 exact-count
// segments in an LDS hash, inject self loops, compact src lists + counts.
extern "C" __global__ __launch_bounds__(256)
void k_dedup(const int* __restrict__ c2, const unsigned int* __restrict__ buf2,
             unsigned int* __restrict__ srclist, int* __restrict__ cnt,
             float* __restrict__ inv){
  __shared__ unsigned int HT[HTS];   // 32KB
  __shared__ int dcur[128];
  __shared__ int m4[NB2];
  const int tid = threadIdx.x;
  const int b   = blockIdx.x;
  const int d0  = b << 7;
  uint4* HT4 = reinterpret_cast<uint4*>(HT);
  #pragma unroll
  for (int r = 0; r < 8; ++r) HT4[r*256 + tid] = make_uint4(EMPTY,EMPTY,EMPTY,EMPTY);
  if (tid < 128) dcur[tid] = 0;
  if (tid < NB2) m4[tid] = c2[b*NB2 + tid];
  __syncthreads();

  const unsigned int* bp = buf2 + (size_t)b * NB2 * S2;
  #pragma unroll
  for (int k = 0; k < NB2; ++k){
    int m = m4[k];
    for (int i = tid; i < m; i += 256){
      unsigned int pk  = bp[k*S2 + i];
      unsigned int idx = mix32(pk) & (HTS-1);
      for (;;){
        unsigned int prev = atomicCAS(&HT[idx], EMPTY, pk);
        if (prev == EMPTY || prev == pk) break;
        idx = (idx + 1) & (HTS-1);
      }
    }
  }
  if (tid < 128 && d0 + tid < NN){      // self loop (src=dst=d0+tid)
    unsigned int pk  = ((unsigned)(d0 + tid) << 7) | (unsigned)tid;
    unsigned int idx = mix32(pk) & (HTS-1);
    for (;;){
      unsigned int prev = atomicCAS(&HT[idx], EMPTY, pk);
      if (prev == EMPTY || prev == pk) break;
      idx = (idx + 1) & (HTS-1);
    }
  }
  __syncthreads();

  // single scan: compact + count
  for (int i = tid; i < HTS; i += 256){
    unsigned int v = HT[i];
    if (v != EMPTY){
      int dl  = v & 127;
      int pos = atomicAdd(&dcur[dl], 1);
      if (pos < CAP) srclist[(size_t)(d0 + dl) * CAP + pos] = v >> 7;
    }
  }
  __syncthreads();
  if (tid < 128 && d0 + tid < NN){
    int c = dcur[tid];
    cnt[d0 + tid] = c;
    inv[d0 + tid] = rsqrtf((float)c);
  }
}

// One wave per dst. lane = dim-PAIR (u32 = 2 bf16); half-wave 0 processes
// even edges, half-wave 1 odd edges; 8 pair-accumulators in flight;
// shfl_xor(32) combine; NT srclist loads + NT float2 store.
extern "C" __global__ __launch_bounds__(256)
void k_agg(const __hip_bfloat16* __restrict__ hb, const float* __restrict__ inv,
           const int* __restrict__ cnt, const unsigned int* __restrict__ srclist,
           float* __restrict__ out){
  __shared__ uint2 sv[4][CAP];   // .x = src, .y = f32 bits of inv[src]
  const int wv   = threadIdx.x >> 6;
  const int lane = threadIdx.x & 63;
  const int half = lane >> 5;
  const int pl   = lane & 31;
  const int d    = blockIdx.x*4 + wv;
  if (d >= NN) return;
  const unsigned int* reg = srclist + (size_t)d * CAP;
  int c = cnt[d]; if (c > CAP) c = CAP;
  const int c16 = (c + 15) & ~15;

  if (lane < c){
    unsigned s = __builtin_nontemporal_load(reg + lane);
    sv[wv][lane] = make_uint2(s, __float_as_uint(inv[s]));
  }
  if (64 + lane < c){
    unsigned s = __builtin_nontemporal_load(reg + 64 + lane);
    sv[wv][64 + lane] = make_uint2(s, __float_as_uint(inv[s]));
  }
  { int p = c + lane; if (p < c16) sv[wv][p] = make_uint2(0u, 0u); }

  const char* hbase = (const char*)hb;
  const int   boff  = pl << 2;    // byte offset of this dim pair within a row
  float ax[8], ay[8];
  #pragma unroll
  for (int u=0;u<8;++u){ ax[u]=0.f; ay[u]=0.f; }
  #pragma unroll 1
  for (int j = 0; j < c16; j += 16){
    #pragma unroll
    for (int u = 0; u < 8; ++u){
      uint2 e = sv[wv][j + 2*u + half];
      float w = __uint_as_float(e.y);
      unsigned hv = *reinterpret_cast<const unsigned*>(hbase + ((size_t)e.x << 7) + boff);
      ax[u] += w * __uint_as_float(hv << 16);
      ay[u] += w * __uint_as_float(hv & 0xFFFF0000u);
    }
  }
  float rx = ((ax[0]+ax[1])+(ax[2]+ax[3])) + ((ax[4]+ax[5])+(ax[6]+ax[7]));
  float ry = ((ay[0]+ay[1])+(ay[2]+ay[3])) + ((ay[4]+ay[5])+(ay[6]+ay[7]));
  rx += __shfl_xor(rx, 32);
  ry += __shfl_xor(ry, 32);
  if (half == 0){
    float iv = inv[d];
    fx2 o; o.x = rx * iv; o.y = ry * iv;
    __builtin_nontemporal_store(o, reinterpret_cast<fx2*>(&out[(size_t)d*64 + (pl << 1)]));
  }
}

extern "C" void kernel_launch(void* const* d_in, const int* in_sizes, int n_in,
                              void* d_out, int out_size, void* d_ws, size_t ws_size,
                              hipStream_t stream){
  (void)in_sizes; (void)n_in; (void)out_size; (void)ws_size;
  const float* x  = (const float*)d_in[0];
  const int*   ei = (const int*)  d_in[1];
  const float* W  = (const float*)d_in[2];
  const float* b  = (const float*)d_in[3];
  float* out = (float*)d_out;

  char* ws = (char*)d_ws;
  __hip_bfloat16* hb      = (__hip_bfloat16*)ws;            // 12.8 MB
  float*          inv     = (float*)(ws + 12800000);        // 0.4 MB
  int*            cnt     = (int*)  (ws + 13200000);        // 0.4 MB
  unsigned int*   srclist = (unsigned int*)(ws + 13600000); // 100K*80*4 = 32 MB
  int*            c1      = (int*)  (ws + 45600000);        // 61*391*4 = 95.4 KB
  unsigned int*   buf1    = (unsigned int*)(ws + 45696000); // 61*391*256*4 = 24.4 MB
  int*            c2      = (int*)  (ws + 70120448);        // 793*4*4 = 12.7 KB
  unsigned int*   buf2    = (unsigned int*)(ws + 70133760); // 793*4*1536*4 = 19.5 MB (end ~89.6 MB)

  k_prep  <<<GBIN + GLIN, 256, 0, stream>>>(x, W, b, hb, ei, c1, buf1);
  k_bin2  <<<NS * NB2, 256, 0, stream>>>(c1, buf1, c2, buf2);
  k_dedup <<<NBF, 256, 0, stream>>>(c2, buf2, srclist, cnt, inv);
  k_agg   <<<(NN + 3)/4, 256, 0, stream>>>(hb, inv, cnt, srclist, out);
}

// Round 14
// 148.310 us; speedup vs baseline: 1.1561x; 1.1561x over previous
//
#include <hip/hip_runtime.h>
#include <hip/hip_bf16.h>
#include <stdint.h>

#define NN 100000
#define EE 1600000
#define CAP 80            // srclist slots per dst (max unique in-degree ~70)
#define NB 782            // ceil(NN/128) dst buckets
#define CAPB 5120         // bucket capacity (mean ~4092, sigma ~64)
#define HTS 8192          // per-bucket LDS hash slots
#define EMPTY 0xFFFFFFFFu
#define BCH 4096          // edge pairs per bin block
#define GBIN 391          // bin blocks: ceil(EE/BCH)
#define GLIN 1563         // linear blocks: ceil(NN/64)

typedef float fx2 __attribute__((ext_vector_type(2)));   // NT-store-compatible

__device__ __forceinline__ unsigned int mix32(unsigned int x){
  x ^= x >> 16; x *= 0x7feb352du;
  x ^= x >> 15; x *= 0x846ca68bu;
  x ^= x >> 16;
  return x;
}

// Fused linear+bin, 17.9KB LDS -> 8 blocks/CU. Bin blocks FIRST (longest-
// job-first). Bin = r7's two-pass (hist -> one global base atomicAdd per
// (block,bucket) -> place), edges held in registers, int4 loads.
extern "C" __global__ __launch_bounds__(256)
void k_prep(const float* __restrict__ x, const float* __restrict__ W,
            const float* __restrict__ bias, __hip_bfloat16* __restrict__ hb,
            const int* __restrict__ ei, int* __restrict__ bcnt,
            unsigned int* __restrict__ bbuf){
  __shared__ __align__(16) char sm[17920];
  const int tid = threadIdx.x;
  const int bid = blockIdx.x;
  const bool isbin = (bid < GBIN);
  const int sub = isbin ? bid : (bid - GBIN);

  if (!isbin){
    // ---------- linear: 64 nodes/block, W and x staged bf16 ----------
    __hip_bfloat16 (*wt)[72] = reinterpret_cast<__hip_bfloat16(*)[72]>(sm);        // 9216B wt[i][o]=W[o][i]
    __hip_bfloat16 (*xs)[68] = reinterpret_cast<__hip_bfloat16(*)[68]>(sm + 9216); // 8704B xs[i][n]
    const int lane = tid & 63;
    const int wv   = tid >> 6;
    #pragma unroll
    for (int r = 0; r < 16; ++r){
      int i = r*4 + wv;
      wt[i][lane] = __float2bfloat16(W[lane*64 + i]);
    }
    const int nbase = sub * 64;
    #pragma unroll
    for (int r = 0; r < 4; ++r){
      int idx = r*256 + tid;          // float4 slot in [64][16]
      int nl  = idx >> 4;
      int c4  = idx & 15;
      int n   = nbase + nl;
      float4 v = make_float4(0.f,0.f,0.f,0.f);
      if (n < NN) v = reinterpret_cast<const float4*>(x)[(size_t)n*16 + c4];
      xs[c4*4+0][nl] = __float2bfloat16(v.x);
      xs[c4*4+1][nl] = __float2bfloat16(v.y);
      xs[c4*4+2][nl] = __float2bfloat16(v.z);
      xs[c4*4+3][nl] = __float2bfloat16(v.w);
    }
    __syncthreads();

    const int og  = tid & 7;
    const int nl0 = (tid >> 3) * 2;   // 2 nodes per thread
    float acc[2][8];
    #pragma unroll
    for (int t=0;t<2;++t){
      #pragma unroll
      for (int j=0;j<8;++j) acc[t][j]=0.f;
    }
    #pragma unroll 4
    for (int i=0;i<64;++i){
      uint4 wq = *reinterpret_cast<const uint4*>(&wt[i][og*8]);
      float w0 = __uint_as_float(wq.x << 16), w1 = __uint_as_float(wq.x & 0xFFFF0000u);
      float w2 = __uint_as_float(wq.y << 16), w3 = __uint_as_float(wq.y & 0xFFFF0000u);
      float w4 = __uint_as_float(wq.z << 16), w5 = __uint_as_float(wq.z & 0xFFFF0000u);
      float w6 = __uint_as_float(wq.w << 16), w7 = __uint_as_float(wq.w & 0xFFFF0000u);
      unsigned xv = *reinterpret_cast<const unsigned*>(&xs[i][nl0]);  // 2 bf16
      float x0 = __uint_as_float(xv << 16);
      float x1 = __uint_as_float(xv & 0xFFFF0000u);
      acc[0][0] += x0*w0; acc[0][1] += x0*w1; acc[0][2] += x0*w2; acc[0][3] += x0*w3;
      acc[0][4] += x0*w4; acc[0][5] += x0*w5; acc[0][6] += x0*w6; acc[0][7] += x0*w7;
      acc[1][0] += x1*w0; acc[1][1] += x1*w1; acc[1][2] += x1*w2; acc[1][3] += x1*w3;
      acc[1][4] += x1*w4; acc[1][5] += x1*w5; acc[1][6] += x1*w6; acc[1][7] += x1*w7;
    }
    float4 b0 = reinterpret_cast<const float4*>(bias)[og*2];
    float4 b1 = reinterpret_cast<const float4*>(bias)[og*2+1];
    float bb[8] = {b0.x,b0.y,b0.z,b0.w,b1.x,b1.y,b1.z,b1.w};
    #pragma unroll
    for (int t=0;t<2;++t){
      int n = nbase + nl0 + t;
      if (n < NN){
        union { uint4 u4; __hip_bfloat16 v[8]; } pk;
        #pragma unroll
        for (int j=0;j<8;++j) pk.v[j] = __float2bfloat16(acc[t][j] + bb[j]);
        reinterpret_cast<uint4*>(&hb[(size_t)n*64])[og] = pk.u4;
      }
    }
  } else {
    // ---------- bin: 4096 pairs/block, two-pass, regs held, int4 loads ----------
    int* hist  = reinterpret_cast<int*>(sm);   // [NB]
    int* bbase = hist + NB;                    // [NB]
    int* bcur  = bbase + NB;                   // [NB]
    for (int i = tid; i < NB; i += 256) hist[i] = 0;
    __syncthreads();
    const int base4 = sub * 1024;
    const int4* ea4 = reinterpret_cast<const int4*>(ei);
    const int4* ec4 = reinterpret_cast<const int4*>(ei + EE);
    int4 A[4], C[4];
    #pragma unroll
    for (int r = 0; r < 4; ++r){
      int idx = base4 + r*256 + tid;
      if (idx < (EE >> 2)){
        A[r] = ea4[idx]; C[r] = ec4[idx];
        atomicAdd(&hist[C[r].x >> 7], 1); atomicAdd(&hist[A[r].x >> 7], 1);
        atomicAdd(&hist[C[r].y >> 7], 1); atomicAdd(&hist[A[r].y >> 7], 1);
        atomicAdd(&hist[C[r].z >> 7], 1); atomicAdd(&hist[A[r].z >> 7], 1);
        atomicAdd(&hist[C[r].w >> 7], 1); atomicAdd(&hist[A[r].w >> 7], 1);
      } else A[r].x = -1;
    }
    __syncthreads();
    for (int bk = tid; bk < NB; bk += 256){
      int hh = hist[bk];
      bbase[bk] = hh ? atomicAdd(&bcnt[bk], hh) : 0;
      bcur[bk]  = 0;
    }
    __syncthreads();
    #pragma unroll
    for (int r = 0; r < 4; ++r){
      if (A[r].x >= 0){
#define PLACE(a,c) { \
        int b1 = (c) >> 7, b2 = (a) >> 7; \
        int p1 = bbase[b1] + atomicAdd(&bcur[b1], 1); \
        int p2 = bbase[b2] + atomicAdd(&bcur[b2], 1); \
        if (p1 < CAPB) bbuf[(size_t)b1*CAPB + p1] = ((unsigned)(a) << 7) | (unsigned)((c) & 127); \
        if (p2 < CAPB) bbuf[(size_t)b2*CAPB + p2] = ((unsigned)(c) << 7) | (unsigned)((a) & 127); }
        PLACE(A[r].x, C[r].x) PLACE(A[r].y, C[r].y)
        PLACE(A[r].z, C[r].z) PLACE(A[r].w, C[r].w)
#undef PLACE
      }
    }
  }
}

// One block per bucket: dedup in LDS hash (uint4 init), inject self loops,
// single scan compacts src lists + counts degrees.
extern "C" __global__ __launch_bounds__(256)
void k_dedup(const int* __restrict__ bcnt, const unsigned int* __restrict__ bbuf,
             unsigned int* __restrict__ srclist, int* __restrict__ cnt,
             float* __restrict__ inv){
  __shared__ unsigned int HT[HTS];   // 32KB
  __shared__ int dcur[128];
  const int tid = threadIdx.x;
  const int b   = blockIdx.x;
  const int d0  = b << 7;
  uint4* HT4 = reinterpret_cast<uint4*>(HT);
  #pragma unroll
  for (int r = 0; r < 8; ++r) HT4[r*256 + tid] = make_uint4(EMPTY,EMPTY,EMPTY,EMPTY);
  if (tid < 128) dcur[tid] = 0;
  __syncthreads();

  int n = bcnt[b]; if (n > CAPB) n = CAPB;
  const unsigned int* buf = bbuf + (size_t)b * CAPB;
  for (int k = tid; k < n; k += 256){
    unsigned int pk  = buf[k];
    unsigned int idx = mix32(pk) & (HTS-1);
    for (;;){
      unsigned int prev = atomicCAS(&HT[idx], EMPTY, pk);
      if (prev == EMPTY || prev == pk) break;
      idx = (idx + 1) & (HTS-1);
    }
  }
  if (tid < 128 && d0 + tid < NN){      // self loop (src=dst=d0+tid)
    unsigned int pk  = ((unsigned)(d0 + tid) << 7) | (unsigned)tid;
    unsigned int idx = mix32(pk) & (HTS-1);
    for (;;){
      unsigned int prev = atomicCAS(&HT[idx], EMPTY, pk);
      if (prev == EMPTY || prev == pk) break;
      idx = (idx + 1) & (HTS-1);
    }
  }
  __syncthreads();

  // single scan: compact + count
  for (int i = tid; i < HTS; i += 256){
    unsigned int v = HT[i];
    if (v != EMPTY){
      int dl  = v & 127;
      int pos = atomicAdd(&dcur[dl], 1);
      if (pos < CAP) srclist[(size_t)(d0 + dl) * CAP + pos] = v >> 7;
    }
  }
  __syncthreads();
  if (tid < 128 && d0 + tid < NN){
    int c = dcur[tid];
    cnt[d0 + tid] = c;
    inv[d0 + tid] = rsqrtf((float)c);
  }
}

// One wave per dst. lane = dim-PAIR (u32 = 2 bf16); half-wave 0 processes
// even edges, half-wave 1 odd edges; 8 pair-accumulators in flight;
// shfl_xor(32) combine; NT srclist loads + NT float2 store.
extern "C" __global__ __launch_bounds__(256)
void k_agg(const __hip_bfloat16* __restrict__ hb, const float* __restrict__ inv,
           const int* __restrict__ cnt, const unsigned int* __restrict__ srclist,
           float* __restrict__ out){
  __shared__ uint2 sv[4][CAP];   // .x = src, .y = f32 bits of inv[src]
  const int wv   = threadIdx.x >> 6;
  const int lane = threadIdx.x & 63;
  const int half = lane >> 5;
  const int pl   = lane & 31;
  const int d    = blockIdx.x*4 + wv;
  if (d >= NN) return;
  const unsigned int* reg = srclist + (size_t)d * CAP;
  int c = cnt[d]; if (c > CAP) c = CAP;
  const int c16 = (c + 15) & ~15;

  if (lane < c){
    unsigned s = __builtin_nontemporal_load(reg + lane);
    sv[wv][lane] = make_uint2(s, __float_as_uint(inv[s]));
  }
  if (64 + lane < c){
    unsigned s = __builtin_nontemporal_load(reg + 64 + lane);
    sv[wv][64 + lane] = make_uint2(s, __float_as_uint(inv[s]));
  }
  { int p = c + lane; if (p < c16) sv[wv][p] = make_uint2(0u, 0u); }

  const char* hbase = (const char*)hb;
  const int   boff  = pl << 2;    // byte offset of this dim pair within a row
  float ax[8], ay[8];
  #pragma unroll
  for (int u=0;u<8;++u){ ax[u]=0.f; ay[u]=0.f; }
  #pragma unroll 1
  for (int j = 0; j < c16; j += 16){
    #pragma unroll
    for (int u = 0; u < 8; ++u){
      uint2 e = sv[wv][j + 2*u + half];
      float w = __uint_as_float(e.y);
      unsigned hv = *reinterpret_cast<const unsigned*>(hbase + ((size_t)e.x << 7) + boff);
      ax[u] += w * __uint_as_float(hv << 16);
      ay[u] += w * __uint_as_float(hv & 0xFFFF0000u);
    }
  }
  float rx = ((ax[0]+ax[1])+(ax[2]+ax[3])) + ((ax[4]+ax[5])+(ax[6]+ax[7]));
  float ry = ((ay[0]+ay[1])+(ay[2]+ay[3])) + ((ay[4]+ay[5])+(ay[6]+ay[7]));
  rx += __shfl_xor(rx, 32);
  ry += __shfl_xor(ry, 32);
  if (half == 0){
    float iv = inv[d];
    fx2 o; o.x = rx * iv; o.y = ry * iv;
    __builtin_nontemporal_store(o, reinterpret_cast<fx2*>(&out[(size_t)d*64 + (pl << 1)]));
  }
}

extern "C" void kernel_launch(void* const* d_in, const int* in_sizes, int n_in,
                              void* d_out, int out_size, void* d_ws, size_t ws_size,
                              hipStream_t stream){
  (void)in_sizes; (void)n_in; (void)out_size; (void)ws_size;
  const float* x  = (const float*)d_in[0];
  const int*   ei = (const int*)  d_in[1];
  const float* W  = (const float*)d_in[2];
  const float* b  = (const float*)d_in[3];
  float* out = (float*)d_out;

  char* ws = (char*)d_ws;
  __hip_bfloat16* hb      = (__hip_bfloat16*)ws;            // 12.8 MB
  float*          inv     = (float*)(ws + 12800000);        // 0.4 MB
  int*            cnt     = (int*)  (ws + 13200000);        // 0.4 MB
  unsigned int*   srclist = (unsigned int*)(ws + 13600000); // 100K*80*4 = 32 MB
  int*            bcnt    = (int*)  (ws + 45600000);        // 4 KB
  unsigned int*   bbuf    = (unsigned int*)(ws + 45604096); // 782*5120*4 = 16 MB (end ~61.6 MB)

  (void)hipMemsetAsync(bcnt, 0, NB * 4, stream);

  k_prep  <<<GBIN + GLIN, 256, 0, stream>>>(x, W, b, hb, ei, bcnt, bbuf);
  k_dedup <<<NB, 256, 0, stream>>>(bcnt, bbuf, srclist, cnt, inv);
  k_agg   <<<(NN + 3)/4, 256, 0, stream>>>(hb, inv, cnt, srclist, out);
}